// Round 2
// baseline (203.422 us; speedup 1.0000x reference)
//
#include <hip/hip_runtime.h>
#include <hip/hip_bf16.h>

// cos(2*pi*t/8), t = 0..7
__device__ const float C8[8] = {
    1.0f, 0.70710678118654752f, 0.0f, -0.70710678118654752f,
   -1.0f, -0.70710678118654752f, 0.0f, 0.70710678118654752f
};

// ---------------- channel mean: x(4,32,512,512) -> xm(4,512,512) ----------------
__global__ __launch_bounds__(256) void k_mean(const float* __restrict__ x,
                                              float* __restrict__ xm) {
    int idx = blockIdx.x * 256 + threadIdx.x;   // float4 index, 262144 total
    int b = idx >> 16;                          // 65536 float4 per batch plane
    int rem = idx & 65535;
    const float4* xp = (const float4*)x + (size_t)b * 32 * 65536 + rem;
    float4 acc = {0.f, 0.f, 0.f, 0.f};
    #pragma unroll 8
    for (int c = 0; c < 32; ++c) {
        float4 v = xp[(size_t)c * 65536];
        acc.x += v.x; acc.y += v.y; acc.z += v.z; acc.w += v.w;
    }
    const float s = 1.0f / 32.0f;
    acc.x *= s; acc.y *= s; acc.z *= s; acc.w *= s;
    ((float4*)xm)[idx] = acc;
}

// ---------------- edge strength per patch: xm -> es(4,64,64) ----------------
__global__ __launch_bounds__(256) void k_edge(const float* __restrict__ xm,
                                              float* __restrict__ es) {
    int b = blockIdx.x >> 6;
    int hti = blockIdx.x & 63;
    int t = threadIdx.x;
    int w = t & 63;     // patch column
    int q = t >> 6;     // quarter: rows q*2, q*2+1 of the patch
    const float* base = xm + (size_t)b * 512 * 512;
    float partial = 0.0f;
    for (int ry = 0; ry < 2; ++ry) {
        int y = hti * 8 + q * 2 + ry;
        for (int x0 = 0; x0 < 8; ++x0) {
            int xx = w * 8 + x0;
            float n[3][3];
            #pragma unroll
            for (int dy = -1; dy <= 1; ++dy) {
                #pragma unroll
                for (int dx = -1; dx <= 1; ++dx) {
                    int yy = y + dy, xc = xx + dx;
                    float v = 0.0f;
                    if (yy >= 0 && yy < 512 && xc >= 0 && xc < 512)
                        v = base[yy * 512 + xc];
                    n[dy + 1][dx + 1] = v;
                }
            }
            float gx = (n[0][2] - n[0][0]) + 2.0f * (n[1][2] - n[1][0]) + (n[2][2] - n[2][0]);
            float gy = (n[2][0] - n[0][0]) + 2.0f * (n[2][1] - n[0][1]) + (n[2][2] - n[0][2]);
            partial += sqrtf(gx * gx + gy * gy + 1e-6f);
        }
    }
    __shared__ float sred[256];
    sred[t] = partial;
    __syncthreads();
    if (t < 64) {
        float s = sred[t] + sred[t + 64] + sred[t + 128] + sred[t + 192];
        es[((size_t)b * 64 + hti) * 64 + t] = s * (1.0f / 64.0f);
    }
}

// ---------------- per-batch normalize: es -> f = (ec-1);  block 4: prep K0/K1 ----------------
__global__ __launch_bounds__(256) void k_coeff_prep(const float* __restrict__ es,
                                                    float* __restrict__ f,
                                                    const float* __restrict__ gain,
                                                    float* __restrict__ Kg) {
    int b = blockIdx.x;
    int t = threadIdx.x;
    if (b == 4) {
        // ---- prep: gain(6) -> K0[64] | K1[64] in Kg ----
        __shared__ float m0[40], m1[40];
        if (t < 40) {
            int ky = t / 5, kx = t % 5;
            int kyp = (ky < 8 - ky) ? ky : (8 - ky);
            float r = sqrtf((float)(kyp * kyp + kx * kx)) / (sqrtf(32.0f) + 1e-8f);
            r = fminf(fmaxf(r, 0.0f), 1.0f);
            float wv[6], wsum = 0.0f;
            #pragma unroll
            for (int i = 0; i < 6; ++i) {
                float c = 0.2f * (float)i;
                float v = fmaxf(1.0f - fabsf(r - c) * 5.0f, 0.0f);
                wv[i] = v; wsum += v;
            }
            float inv = 1.0f / (wsum + 1e-8f);
            float acc = 0.0f;
            #pragma unroll
            for (int i = 0; i < 6; ++i) acc += wv[i] * inv * gain[i];
            float mask = fmaxf(acc, 0.0f);
            m0[t] = mask;
            m1[t] = (r >= 0.6f) ? mask : 0.0f;
        }
        __syncthreads();
        if (t < 64) {
            int a = t >> 3, bb = t & 7;
            float s0 = 0.0f, s1 = 0.0f;
            for (int ky = 0; ky < 8; ++ky) {
                for (int kx = 0; kx < 8; ++kx) {
                    int kxh = (kx <= 4) ? kx : (8 - kx);
                    float c = C8[(ky * a + kx * bb) & 7];
                    s0 += m0[ky * 5 + kxh] * c;
                    s1 += m1[ky * 5 + kxh] * c;
                }
            }
            Kg[t] = s0 * (1.0f / 64.0f);
            Kg[64 + t] = s1 * (1.0f / 64.0f);
        }
        return;
    }
    const float* e = es + (size_t)b * 4096;
    float mn = 1e30f, mx = -1e30f;
    for (int i = t; i < 4096; i += 256) {
        float v = e[i];
        mn = fminf(mn, v); mx = fmaxf(mx, v);
    }
    #pragma unroll
    for (int off = 32; off > 0; off >>= 1) {
        mn = fminf(mn, __shfl_down(mn, off));
        mx = fmaxf(mx, __shfl_down(mx, off));
    }
    __shared__ float smn[4], smx[4];
    if ((t & 63) == 0) { smn[t >> 6] = mn; smx[t >> 6] = mx; }
    __syncthreads();
    mn = fminf(fminf(smn[0], smn[1]), fminf(smn[2], smn[3]));
    mx = fmaxf(fmaxf(smx[0], smx[1]), fmaxf(smx[2], smx[3]));
    float scale = 0.5f / (mx - mn + 1e-6f);
    for (int i = t; i < 4096; i += 256) {
        f[(size_t)b * 4096 + i] = (e[i] - mn) * scale;
    }
}

// ---------------- main: per-patch circular conv with K_eff = K0 + f*K1 ----------------
// Register plan: p[64] (patch) + K[64] + acc[8] + addressing ~ 150 VGPR.
// __launch_bounds__(256,3): allow ~168 VGPRs (3 waves/SIMD), avoid scratch spills.
__global__ __launch_bounds__(256, 3) void k_main(const float* __restrict__ x,
                                                 const float* __restrict__ Kg,
                                                 const float* __restrict__ f,
                                                 float* __restrict__ out) {
    // grid: 2048 = b(4) * hti(64) * cg(8); block 256: w(64) x cloc(4)
    int blk = blockIdx.x;
    int cg = blk & 7;
    int hti = (blk >> 3) & 63;
    int b = blk >> 9;
    int t = threadIdx.x;
    int w = t & 63;
    int c = cg * 4 + (t >> 6);

    float fc = f[((size_t)b * 64 + hti) * 64 + w];

    float K[64];
    #pragma unroll
    for (int i = 0; i < 64; i += 4) {
        float4 k0 = *(const float4*)(Kg + i);
        float4 k1 = *(const float4*)(Kg + 64 + i);
        K[i + 0] = fmaf(fc, k1.x, k0.x);
        K[i + 1] = fmaf(fc, k1.y, k0.y);
        K[i + 2] = fmaf(fc, k1.z, k0.z);
        K[i + 3] = fmaf(fc, k1.w, k0.w);
    }

    size_t ofs = (((size_t)(b * 32 + c) * 512) + (size_t)hti * 8) * 512 + w * 8;
    const float* src = x + ofs;
    float* dst = out + ofs;

    float p[64];
    #pragma unroll
    for (int a = 0; a < 8; ++a) {
        float4 p0 = *(const float4*)(src + a * 512);
        float4 p1 = *(const float4*)(src + a * 512 + 4);
        p[a * 8 + 0] = p0.x; p[a * 8 + 1] = p0.y; p[a * 8 + 2] = p0.z; p[a * 8 + 3] = p0.w;
        p[a * 8 + 4] = p1.x; p[a * 8 + 5] = p1.y; p[a * 8 + 6] = p1.z; p[a * 8 + 7] = p1.w;
    }

    #pragma unroll
    for (int y = 0; y < 8; ++y) {
        float acc[8];
        #pragma unroll
        for (int xx = 0; xx < 8; ++xx) acc[xx] = 0.0f;
        #pragma unroll
        for (int a = 0; a < 8; ++a) {
            const int kr = ((y - a) & 7) * 8;
            #pragma unroll
            for (int bb = 0; bb < 8; ++bb) {
                const float pv = p[a * 8 + bb];
                #pragma unroll
                for (int xx = 0; xx < 8; ++xx) {
                    acc[xx] = fmaf(pv, K[kr + ((xx - bb) & 7)], acc[xx]);
                }
            }
        }
        float4 o0 = {acc[0], acc[1], acc[2], acc[3]};
        float4 o1 = {acc[4], acc[5], acc[6], acc[7]};
        *(float4*)(dst + y * 512) = o0;
        *(float4*)(dst + y * 512 + 4) = o1;
    }
}

extern "C" void kernel_launch(void* const* d_in, const int* in_sizes, int n_in,
                              void* d_out, int out_size, void* d_ws, size_t ws_size,
                              hipStream_t stream) {
    const float* x    = (const float*)d_in[0];   // (4,32,512,512)
    const float* gain = (const float*)d_in[1];   // (1,6)
    float* out = (float*)d_out;
    float* ws = (float*)d_ws;

    float* Kg = ws;                      // 128 floats: K0 | K1
    float* f  = ws + 128;                // 4*4096
    float* es = ws + 128 + 16384;        // 4*4096
    float* xm = ws + 128 + 2 * 16384;    // 4*512*512

    hipLaunchKernelGGL(k_mean, dim3(1024), dim3(256), 0, stream, x, xm);
    hipLaunchKernelGGL(k_edge, dim3(256), dim3(256), 0, stream, xm, es);
    hipLaunchKernelGGL(k_coeff_prep, dim3(5), dim3(256), 0, stream, es, f, gain, Kg);
    hipLaunchKernelGGL(k_main, dim3(2048), dim3(256), 0, stream, x, Kg, f, out);
}

// Round 3
// 103.789 us; speedup vs baseline: 1.9600x; 1.9600x over previous
//
#include <hip/hip_runtime.h>
#include <hip/hip_bf16.h>

// cos(2*pi*t/8), t = 0..7
__device__ const float C8[8] = {
    1.0f, 0.70710678118654752f, 0.0f, -0.70710678118654752f,
   -1.0f, -0.70710678118654752f, 0.0f, 0.70710678118654752f
};

// Unique-id map for the 8x8 circular-conv kernel, which is even in both axes
// and symmetric under (dy,dx) swap: 15 unique values for d1<=d2 in [0,4].
__host__ __device__ constexpr int kid(int dy, int dx) {
    int a = (dy < 8 - dy) ? dy : 8 - dy;
    int b = (dx < 8 - dx) ? dx : 8 - dx;
    int lo = a < b ? a : b, hi = a < b ? b : a;
    return lo * 5 - lo * (lo - 1) / 2 + (hi - lo);
}

// ---------------- channel mean: x(4,32,512,512) -> xm(4,512,512) ----------------
__global__ __launch_bounds__(256) void k_mean(const float* __restrict__ x,
                                              float* __restrict__ xm) {
    int idx = blockIdx.x * 256 + threadIdx.x;   // float4 index, 262144 total
    int b = idx >> 16;                          // 65536 float4 per batch plane
    int rem = idx & 65535;
    const float4* xp = (const float4*)x + (size_t)b * 32 * 65536 + rem;
    float4 acc = {0.f, 0.f, 0.f, 0.f};
    #pragma unroll 8
    for (int c = 0; c < 32; ++c) {
        float4 v = xp[(size_t)c * 65536];
        acc.x += v.x; acc.y += v.y; acc.z += v.z; acc.w += v.w;
    }
    const float s = 1.0f / 32.0f;
    acc.x *= s; acc.y *= s; acc.z *= s; acc.w *= s;
    ((float4*)xm)[idx] = acc;
}

// ---------------- edge strength per patch: xm -> es(4,64,64) ----------------
__global__ __launch_bounds__(256) void k_edge(const float* __restrict__ xm,
                                              float* __restrict__ es) {
    int b = blockIdx.x >> 6;
    int hti = blockIdx.x & 63;
    int t = threadIdx.x;
    int w = t & 63;     // patch column
    int q = t >> 6;     // quarter: rows q*2, q*2+1 of the patch
    const float* base = xm + (size_t)b * 512 * 512;
    float partial = 0.0f;
    for (int ry = 0; ry < 2; ++ry) {
        int y = hti * 8 + q * 2 + ry;
        for (int x0 = 0; x0 < 8; ++x0) {
            int xx = w * 8 + x0;
            float n[3][3];
            #pragma unroll
            for (int dy = -1; dy <= 1; ++dy) {
                #pragma unroll
                for (int dx = -1; dx <= 1; ++dx) {
                    int yy = y + dy, xc = xx + dx;
                    float v = 0.0f;
                    if (yy >= 0 && yy < 512 && xc >= 0 && xc < 512)
                        v = base[yy * 512 + xc];
                    n[dy + 1][dx + 1] = v;
                }
            }
            float gx = (n[0][2] - n[0][0]) + 2.0f * (n[1][2] - n[1][0]) + (n[2][2] - n[2][0]);
            float gy = (n[2][0] - n[0][0]) + 2.0f * (n[2][1] - n[0][1]) + (n[2][2] - n[0][2]);
            partial += sqrtf(gx * gx + gy * gy + 1e-6f);
        }
    }
    __shared__ float sred[256];
    sred[t] = partial;
    __syncthreads();
    if (t < 64) {
        float s = sred[t] + sred[t + 64] + sred[t + 128] + sred[t + 192];
        es[((size_t)b * 64 + hti) * 64 + t] = s * (1.0f / 64.0f);
    }
}

// ---------------- per-batch normalize: es -> f = (ec-1);  block 4: prep K0/K1 ----------------
__global__ __launch_bounds__(256) void k_coeff_prep(const float* __restrict__ es,
                                                    float* __restrict__ f,
                                                    const float* __restrict__ gain,
                                                    float* __restrict__ Kg) {
    int b = blockIdx.x;
    int t = threadIdx.x;
    if (b == 4) {
        // ---- prep: gain(6) -> K0[64] | K1[64] in Kg ----
        __shared__ float m0[40], m1[40];
        if (t < 40) {
            int ky = t / 5, kx = t % 5;
            int kyp = (ky < 8 - ky) ? ky : (8 - ky);
            float r = sqrtf((float)(kyp * kyp + kx * kx)) / (sqrtf(32.0f) + 1e-8f);
            r = fminf(fmaxf(r, 0.0f), 1.0f);
            float wv[6], wsum = 0.0f;
            #pragma unroll
            for (int i = 0; i < 6; ++i) {
                float c = 0.2f * (float)i;
                float v = fmaxf(1.0f - fabsf(r - c) * 5.0f, 0.0f);
                wv[i] = v; wsum += v;
            }
            float inv = 1.0f / (wsum + 1e-8f);
            float acc = 0.0f;
            #pragma unroll
            for (int i = 0; i < 6; ++i) acc += wv[i] * inv * gain[i];
            float mask = fmaxf(acc, 0.0f);
            m0[t] = mask;
            m1[t] = (r >= 0.6f) ? mask : 0.0f;
        }
        __syncthreads();
        if (t < 64) {
            int a = t >> 3, bb = t & 7;
            float s0 = 0.0f, s1 = 0.0f;
            for (int ky = 0; ky < 8; ++ky) {
                for (int kx = 0; kx < 8; ++kx) {
                    int kxh = (kx <= 4) ? kx : (8 - kx);
                    float c = C8[(ky * a + kx * bb) & 7];
                    s0 += m0[ky * 5 + kxh] * c;
                    s1 += m1[ky * 5 + kxh] * c;
                }
            }
            Kg[t] = s0 * (1.0f / 64.0f);
            Kg[64 + t] = s1 * (1.0f / 64.0f);
        }
        return;
    }
    const float* e = es + (size_t)b * 4096;
    float mn = 1e30f, mx = -1e30f;
    for (int i = t; i < 4096; i += 256) {
        float v = e[i];
        mn = fminf(mn, v); mx = fmaxf(mx, v);
    }
    #pragma unroll
    for (int off = 32; off > 0; off >>= 1) {
        mn = fminf(mn, __shfl_down(mn, off));
        mx = fmaxf(mx, __shfl_down(mx, off));
    }
    __shared__ float smn[4], smx[4];
    if ((t & 63) == 0) { smn[t >> 6] = mn; smx[t >> 6] = mx; }
    __syncthreads();
    mn = fminf(fminf(smn[0], smn[1]), fminf(smn[2], smn[3]));
    mx = fmaxf(fmaxf(smx[0], smx[1]), fmaxf(smx[2], smx[3]));
    float scale = 0.5f / (mx - mn + 1e-6f);
    for (int i = t; i < 4096; i += 256) {
        f[(size_t)b * 4096 + i] = (e[i] - mn) * scale;
    }
}

// ---------------- main: per-patch circular conv with K_eff = K0 + f*K1 ----------------
// K_eff has only 15 unique values (even in dy,dx + swap symmetry). Live set:
// acc[64] + k[15] + pr[8] + addressing ~= 95 VGPR -> no spill at default cap.
__global__ __launch_bounds__(256) void k_main(const float* __restrict__ x,
                                              const float* __restrict__ Kg,
                                              const float* __restrict__ f,
                                              float* __restrict__ out) {
    // grid: 2048 = b(4) * hti(64) * cg(8); block 256: w(64) x cloc(4)
    int blk = blockIdx.x;
    int cg = blk & 7;
    int hti = (blk >> 3) & 63;
    int b = blk >> 9;
    int t = threadIdx.x;
    int w = t & 63;
    int c = cg * 4 + (t >> 6);

    float fc = f[((size_t)b * 64 + hti) * 64 + w];

    // build the 15 unique kernel values (Kg reads are wave-uniform -> s_load)
    float k[15];
    #pragma unroll
    for (int a = 0; a <= 4; ++a) {
        #pragma unroll
        for (int d = a; d <= 4; ++d) {
            k[kid(a, d)] = fmaf(fc, Kg[64 + a * 8 + d], Kg[a * 8 + d]);
        }
    }

    size_t ofs = (((size_t)(b * 32 + c) * 512) + (size_t)hti * 8) * 512 + w * 8;
    const float* src = x + ofs;
    float* dst = out + ofs;

    float acc[64];
    #pragma unroll
    for (int i = 0; i < 64; ++i) acc[i] = 0.0f;

    #pragma unroll
    for (int a = 0; a < 8; ++a) {
        float4 p0 = *(const float4*)(src + a * 512);
        float4 p1 = *(const float4*)(src + a * 512 + 4);
        float pr[8] = {p0.x, p0.y, p0.z, p0.w, p1.x, p1.y, p1.z, p1.w};
        #pragma unroll
        for (int y = 0; y < 8; ++y) {
            const int dy = (y - a) & 7;
            #pragma unroll
            for (int bb = 0; bb < 8; ++bb) {
                const float pv = pr[bb];
                #pragma unroll
                for (int xx = 0; xx < 8; ++xx) {
                    acc[y * 8 + xx] = fmaf(pv, k[kid(dy, (xx - bb) & 7)], acc[y * 8 + xx]);
                }
            }
        }
    }

    #pragma unroll
    for (int y = 0; y < 8; ++y) {
        float4 o0 = {acc[y * 8 + 0], acc[y * 8 + 1], acc[y * 8 + 2], acc[y * 8 + 3]};
        float4 o1 = {acc[y * 8 + 4], acc[y * 8 + 5], acc[y * 8 + 6], acc[y * 8 + 7]};
        *(float4*)(dst + y * 512) = o0;
        *(float4*)(dst + y * 512 + 4) = o1;
    }
}

extern "C" void kernel_launch(void* const* d_in, const int* in_sizes, int n_in,
                              void* d_out, int out_size, void* d_ws, size_t ws_size,
                              hipStream_t stream) {
    const float* x    = (const float*)d_in[0];   // (4,32,512,512)
    const float* gain = (const float*)d_in[1];   // (1,6)
    float* out = (float*)d_out;
    float* ws = (float*)d_ws;

    float* Kg = ws;                      // 128 floats: K0 | K1
    float* f  = ws + 128;                // 4*4096
    float* es = ws + 128 + 16384;        // 4*4096
    float* xm = ws + 128 + 2 * 16384;    // 4*512*512

    hipLaunchKernelGGL(k_mean, dim3(1024), dim3(256), 0, stream, x, xm);
    hipLaunchKernelGGL(k_edge, dim3(256), dim3(256), 0, stream, xm, es);
    hipLaunchKernelGGL(k_coeff_prep, dim3(5), dim3(256), 0, stream, es, f, gain, Kg);
    hipLaunchKernelGGL(k_main, dim3(2048), dim3(256), 0, stream, x, Kg, f, out);
}